// Round 1
// baseline (304.553 us; speedup 1.0000x reference)
//
#include <hip/hip_runtime.h>
#include <hip/hip_bf16.h>

// B=4, Q=K=1024, C=512, H=8, HD=64, OUT=512
// d_out = [output (4*1024*512 f32) | logits_update (4*8*1024*1024 f32)]

typedef float f32x4 __attribute__((ext_vector_type(4)));
typedef __bf16 bf16x8 __attribute__((ext_vector_type(8)));

static __device__ __forceinline__ __bf16 f2bf(float x) {
    union { float f; unsigned int u; } c; c.f = x;
    unsigned int r = (c.u + 0x7fffu + ((c.u >> 16) & 1u)) >> 16;
    union { unsigned short s; __bf16 b; } o; o.s = (unsigned short)r;
    return o.b;
}

// ---------------------------------------------------------------------------
// Kernel 0: cast data to bf16; transpose weights to (n, k) bf16 layout.
// qw_t gets the 1/8 (= HD^-0.5) scale folded in.
// ---------------------------------------------------------------------------
__global__ __launch_bounds__(256) void cast_kernel(
    const float* __restrict__ qd, const float* __restrict__ md,
    const float* __restrict__ qw, const float* __restrict__ kw,
    const float* __restrict__ vw, const float* __restrict__ gw,
    const float* __restrict__ ow,
    __bf16* __restrict__ qd_b, __bf16* __restrict__ md_b,
    __bf16* __restrict__ qw_t, __bf16* __restrict__ kw_t,
    __bf16* __restrict__ vw_t, __bf16* __restrict__ gw_t,
    __bf16* __restrict__ ow_t)
{
    const int i = blockIdx.x * blockDim.x + threadIdx.x;
    const int stride = gridDim.x * blockDim.x;
    const int NDATA = 4096 * 512;
    for (int idx = i; idx < NDATA; idx += stride) {
        qd_b[idx] = f2bf(qd[idx]);
        md_b[idx] = f2bf(md[idx]);
    }
    // weights: 512x512, transpose (a,n) -> (n,a)
    for (int idx = i; idx < 512 * 512; idx += stride) {
        int n = idx >> 9, a = idx & 511;
        qw_t[idx] = f2bf(qw[a * 512 + n] * 0.125f);
        kw_t[idx] = f2bf(kw[a * 512 + n]);
        vw_t[idx] = f2bf(vw[a * 512 + n]);
        gw_t[idx] = f2bf(gw[a * 512 + n]);
        // ow_t[o][n2] = ow[n2][o] ; here idx = o*512 + n2
        ow_t[idx] = f2bf(ow[(idx & 511) * 512 + (idx >> 9)]);
    }
}

// ---------------------------------------------------------------------------
// Generic bf16 GEMM: C[m,n] = sum_k A[m,k]*Bt[n,k], M=4096, N=K=512.
// 64x64 tile per 256-thread block; wave w computes rows w*16..w*16+15 x 64 n.
// mode 0: store bf16 to outb in (b,h,pos,c) layout   (q_buf / k_buf)
// mode 2: store bf16 to outb in (b,h,c,pos) layout   (v_t, transposed)
// mode 3: sigmoid(x + bvec[n]) -> outb[m*512+n]      (gate)
// mode 4: x + bvec[n] -> outf[m*512+n] (f32)         (final output)
// ---------------------------------------------------------------------------
__global__ __launch_bounds__(256) void gemm512(
    const __bf16* __restrict__ A, const __bf16* __restrict__ Bt,
    float* __restrict__ outf, __bf16* __restrict__ outb,
    const float* __restrict__ bvec, int mode)
{
    __shared__ __attribute__((aligned(16))) __bf16 As[64 * 32];
    __shared__ __attribute__((aligned(16))) __bf16 Bs[64 * 32];
    const int t = threadIdx.x;
    const int lane = t & 63, w = t >> 6;
    const int quad = lane >> 4, col = lane & 15;
    const int m0 = blockIdx.x * 64, n0 = blockIdx.y * 64;
    const int sr = t >> 2, sc = (t & 3) * 8;

    f32x4 acc[4];
#pragma unroll
    for (int i = 0; i < 4; i++) acc[i] = (f32x4){0.f, 0.f, 0.f, 0.f};

    for (int kk = 0; kk < 512; kk += 32) {
        __syncthreads();
        *(bf16x8*)&As[sr * 32 + sc] = *(const bf16x8*)&A[(m0 + sr) * 512 + kk + sc];
        *(bf16x8*)&Bs[sr * 32 + sc] = *(const bf16x8*)&Bt[(n0 + sr) * 512 + kk + sc];
        __syncthreads();
        bf16x8 af = *(const bf16x8*)&As[(w * 16 + col) * 32 + quad * 8];
#pragma unroll
        for (int ns = 0; ns < 4; ns++) {
            bf16x8 bfr = *(const bf16x8*)&Bs[(ns * 16 + col) * 32 + quad * 8];
            acc[ns] = __builtin_amdgcn_mfma_f32_16x16x32_bf16(af, bfr, acc[ns], 0, 0, 0);
        }
    }

    const int mrow0 = m0 + w * 16 + quad * 4;
#pragma unroll
    for (int ns = 0; ns < 4; ns++) {
        const int ncol = n0 + ns * 16 + col;
#pragma unroll
        for (int r = 0; r < 4; r++) {
            const int m = mrow0 + r;
            float v = acc[ns][r];
            if (mode == 0) {
                int b = m >> 10, pos = m & 1023, hh = ncol >> 6, c = ncol & 63;
                outb[(((b * 8 + hh) * 1024 + pos) << 6) + c] = f2bf(v);
            } else if (mode == 2) {
                int b = m >> 10, pos = m & 1023, hh = ncol >> 6, c = ncol & 63;
                outb[((((b * 8 + hh) << 6) + c) << 10) + pos] = f2bf(v);
            } else if (mode == 3) {
                float g = 1.0f / (1.0f + __expf(-(v + bvec[ncol])));
                outb[m * 512 + ncol] = f2bf(g);
            } else {
                outf[m * 512 + ncol] = v + bvec[ncol];
            }
        }
    }
}

// ---------------------------------------------------------------------------
// Attention: per block (b,h, 64 q-rows). Flash-style over 16 key-blocks of 64.
// Writes raw logits (pre-bias) to d_out, weighted*gate (bf16) to wavg.
// ---------------------------------------------------------------------------
__global__ __launch_bounds__(256) void attn_kernel(
    const __bf16* __restrict__ qb, const __bf16* __restrict__ kb,
    const __bf16* __restrict__ vt, const float* __restrict__ bias,
    const float* __restrict__ nb, const __bf16* __restrict__ gate,
    float* __restrict__ logits_out, __bf16* __restrict__ wout)
{
    __shared__ __attribute__((aligned(16))) __bf16 qs[64 * 64];
    __shared__ __attribute__((aligned(16))) __bf16 ks[64 * 64];
    __shared__ __attribute__((aligned(16))) __bf16 vs[64 * 64];
    __shared__ __attribute__((aligned(16))) __bf16 ps[4 * 16 * 64];

    const int bh = blockIdx.y;          // 0..31
    const int b = bh >> 3, h = bh & 7;
    const int q0 = blockIdx.x * 64;     // 0..1023
    const int t = threadIdx.x;
    const int lane = t & 63, w = t >> 6;
    const int quad = lane >> 4, col = lane & 15;

    const __bf16* qg = qb + (bh * 1024 + q0) * 64;
    const __bf16* kg = kb + bh * 65536;
    const __bf16* vg = vt + bh * 65536;
    float* lg = logits_out + (size_t)(bh * 1024 + q0) * 1024;
    const float* nbg = nb + (size_t)(h * 1024 + q0) * 1024;
    const float* biasg = bias + b * 1024;

    // stage q tile (contiguous 8 KiB)
    for (int ch = t; ch < 512; ch += 256)
        *(bf16x8*)&qs[ch * 8] = *(const bf16x8*)&qg[ch * 8];

    f32x4 o_acc[4];
#pragma unroll
    for (int i = 0; i < 4; i++) o_acc[i] = (f32x4){0.f, 0.f, 0.f, 0.f};
    float m_i[4] = {-1e30f, -1e30f, -1e30f, -1e30f};
    float l_i[4] = {0.f, 0.f, 0.f, 0.f};

    __bf16* pw = &ps[w * 1024];

    for (int kbi = 0; kbi < 16; kbi++) {
        __syncthreads();
        // stage k block (contiguous 8 KiB)
        for (int ch = t; ch < 512; ch += 256)
            *(bf16x8*)&ks[ch * 8] = *(const bf16x8*)&kg[kbi * 4096 + ch * 8];
        // stage v block (64 c-rows x 64 keys from (c, kpos) layout)
        for (int ch = t; ch < 512; ch += 256) {
            int c = ch >> 3, off = (ch & 7) * 8;
            *(bf16x8*)&vs[c * 64 + off] = *(const bf16x8*)&vg[c * 1024 + kbi * 64 + off];
        }
        __syncthreads();

        // S = q @ k^T : wave w covers q-rows w*16..+15 x 64 keys
        f32x4 s[4];
#pragma unroll
        for (int i = 0; i < 4; i++) s[i] = (f32x4){0.f, 0.f, 0.f, 0.f};
#pragma unroll
        for (int kst = 0; kst < 2; kst++) {
            bf16x8 af = *(const bf16x8*)&qs[(w * 16 + col) * 64 + kst * 32 + quad * 8];
#pragma unroll
            for (int ns = 0; ns < 4; ns++) {
                bf16x8 bfr = *(const bf16x8*)&ks[(ns * 16 + col) * 64 + kst * 32 + quad * 8];
                s[ns] = __builtin_amdgcn_mfma_f32_16x16x32_bf16(af, bfr, s[ns], 0, 0, 0);
            }
        }

        // write raw logits, add biases, block row-max
        float sv[4][4];
        float bm[4] = {-1e30f, -1e30f, -1e30f, -1e30f};
#pragma unroll
        for (int ns = 0; ns < 4; ns++) {
            const int kcol = kbi * 64 + ns * 16 + col;
            const float bval = biasg[kcol];
#pragma unroll
            for (int r = 0; r < 4; r++) {
                const int row = w * 16 + quad * 4 + r;
                float raw = s[ns][r];
                lg[row * 1024 + kcol] = raw;
                float x = raw + bval + nbg[row * 1024 + kcol];
                sv[ns][r] = x;
                bm[r] = fmaxf(bm[r], x);
            }
        }
#pragma unroll
        for (int mask = 1; mask < 16; mask <<= 1) {
#pragma unroll
            for (int r = 0; r < 4; r++) bm[r] = fmaxf(bm[r], __shfl_xor(bm[r], mask));
        }
        float alpha[4], rs[4];
#pragma unroll
        for (int r = 0; r < 4; r++) {
            float mn = fmaxf(m_i[r], bm[r]);
            alpha[r] = __expf(m_i[r] - mn);
            m_i[r] = mn;
            rs[r] = 0.f;
        }
        // P = exp(sv - m), stash bf16 into per-wave LDS (A-layout round trip)
#pragma unroll
        for (int ns = 0; ns < 4; ns++) {
#pragma unroll
            for (int r = 0; r < 4; r++) {
                float p = __expf(sv[ns][r] - m_i[r]);
                rs[r] += p;
                pw[(quad * 4 + r) * 64 + ns * 16 + col] = f2bf(p);
            }
        }
#pragma unroll
        for (int mask = 1; mask < 16; mask <<= 1) {
#pragma unroll
            for (int r = 0; r < 4; r++) rs[r] += __shfl_xor(rs[r], mask);
        }
#pragma unroll
        for (int r = 0; r < 4; r++) l_i[r] = l_i[r] * alpha[r] + rs[r];
#pragma unroll
        for (int ns = 0; ns < 4; ns++) {
#pragma unroll
            for (int r = 0; r < 4; r++) o_acc[ns][r] *= alpha[r];
        }
        // O += P @ V  (A from pw, B from vs: n = c_out, k = key)
#pragma unroll
        for (int kst = 0; kst < 2; kst++) {
            bf16x8 af = *(const bf16x8*)&pw[col * 64 + kst * 32 + quad * 8];
#pragma unroll
            for (int ns = 0; ns < 4; ns++) {
                bf16x8 vf = *(const bf16x8*)&vs[(ns * 16 + col) * 64 + kst * 32 + quad * 8];
                o_acc[ns] = __builtin_amdgcn_mfma_f32_16x16x32_bf16(af, vf, o_acc[ns], 0, 0, 0);
            }
        }
    }

    // normalize, gate, store weighted (bf16, (b,pos,h,c) = m x 512 layout)
    float inv[4];
#pragma unroll
    for (int r = 0; r < 4; r++) inv[r] = 1.0f / l_i[r];
#pragma unroll
    for (int ns = 0; ns < 4; ns++) {
        const int c = ns * 16 + col;
#pragma unroll
        for (int r = 0; r < 4; r++) {
            const int pos = q0 + w * 16 + quad * 4 + r;
            float ov = o_acc[ns][r] * inv[r];
            float gv = (float)gate[((b * 1024 + pos) * 8 + h) * 64 + c];
            wout[(b * 1024 + pos) * 512 + h * 64 + c] = f2bf(ov * gv);
        }
    }
}

// ---------------------------------------------------------------------------
extern "C" void kernel_launch(void* const* d_in, const int* in_sizes, int n_in,
                              void* d_out, int out_size, void* d_ws, size_t ws_size,
                              hipStream_t stream) {
    (void)in_sizes; (void)n_in; (void)out_size; (void)ws_size;
    const float* q_data   = (const float*)d_in[0];
    const float* m_data   = (const float*)d_in[1];
    const float* bias     = (const float*)d_in[2];
    const float* nbb      = (const float*)d_in[3];
    const float* query_w  = (const float*)d_in[4];
    const float* key_w    = (const float*)d_in[5];
    const float* value_w  = (const float*)d_in[6];
    const float* gating_w = (const float*)d_in[7];
    const float* gating_b = (const float*)d_in[8];
    const float* output_w = (const float*)d_in[9];
    const float* output_b = (const float*)d_in[10];

    char* ws = (char*)d_ws;
    __bf16* qd_b  = (__bf16*)(ws + 0);         // 4 MiB (reused as wavg later)
    __bf16* md_b  = (__bf16*)(ws + 4194304);   // 4 MiB
    __bf16* qw_t  = (__bf16*)(ws + 8388608);   // 512 KiB
    __bf16* kw_t  = (__bf16*)(ws + 8912896);
    __bf16* vw_t  = (__bf16*)(ws + 9437184);
    __bf16* gw_t  = (__bf16*)(ws + 9961472);
    __bf16* ow_t  = (__bf16*)(ws + 10485760);
    __bf16* q_buf = (__bf16*)(ws + 11010048);  // 4 MiB (b,h,pos,c)
    __bf16* k_buf = (__bf16*)(ws + 15204352);  // 4 MiB (b,h,pos,c)
    __bf16* v_t   = (__bf16*)(ws + 19398656);  // 4 MiB (b,h,c,pos)
    __bf16* gate  = (__bf16*)(ws + 23592960);  // 4 MiB (m,512)
    __bf16* wavg  = (__bf16*)(ws + 0);         // overlays qd_b (dead by then)

    float* outp = (float*)d_out;
    float* logits = outp + (4 * 1024 * 512);

    cast_kernel<<<dim3(512), dim3(256), 0, stream>>>(
        q_data, m_data, query_w, key_w, value_w, gating_w, output_w,
        qd_b, md_b, qw_t, kw_t, vw_t, gw_t, ow_t);

    gemm512<<<dim3(64, 8), dim3(256), 0, stream>>>(qd_b, qw_t, nullptr, q_buf, nullptr, 0);
    gemm512<<<dim3(64, 8), dim3(256), 0, stream>>>(md_b, kw_t, nullptr, k_buf, nullptr, 0);
    gemm512<<<dim3(64, 8), dim3(256), 0, stream>>>(md_b, vw_t, nullptr, v_t,   nullptr, 2);
    gemm512<<<dim3(64, 8), dim3(256), 0, stream>>>(qd_b, gw_t, nullptr, gate,  gating_b, 3);

    attn_kernel<<<dim3(16, 32), dim3(256), 0, stream>>>(
        q_buf, k_buf, v_t, bias, nbb, gate, logits, wavg);

    gemm512<<<dim3(64, 8), dim3(256), 0, stream>>>(wavg, ow_t, outp, nullptr, output_b, 4);
}

// Round 2
// 264.872 us; speedup vs baseline: 1.1498x; 1.1498x over previous
//
#include <hip/hip_runtime.h>
#include <hip/hip_bf16.h>

// B=4, Q=K=1024, C=512, H=8, HD=64, OUT=512
// d_out = [output (4*1024*512 f32) | logits_update (4*8*1024*1024 f32)]

typedef float f32x4 __attribute__((ext_vector_type(4)));
typedef __bf16 bf16x8 __attribute__((ext_vector_type(8)));
typedef __bf16 bf16x4 __attribute__((ext_vector_type(4)));

static __device__ __forceinline__ __bf16 f2bf(float x) {
    union { float f; unsigned int u; } c; c.f = x;
    unsigned int r = (c.u + 0x7fffu + ((c.u >> 16) & 1u)) >> 16;
    union { unsigned short s; __bf16 b; } o; o.s = (unsigned short)r;
    return o.b;
}

// async global->LDS, 16B per lane; LDS dest = wave-uniform base + lane*16
static __device__ __forceinline__ void async16(const void* g, void* l) {
    __builtin_amdgcn_global_load_lds(
        (const __attribute__((address_space(1))) void*)g,
        (__attribute__((address_space(3))) void*)l, 16, 0, 0);
}

// ---------------------------------------------------------------------------
// Cast q_data/m_data f32 -> bf16, vectorized (8 elem/thread each).
// ---------------------------------------------------------------------------
__global__ __launch_bounds__(256) void cast_data(
    const float* __restrict__ qd, const float* __restrict__ md,
    __bf16* __restrict__ qdb, __bf16* __restrict__ mdb)
{
    const int i = blockIdx.x * 256 + threadIdx.x;   // 0..262143
    const f32x4* q4 = (const f32x4*)qd;
    const f32x4* m4 = (const f32x4*)md;
    f32x4 a = q4[2 * i], b = q4[2 * i + 1];
    bf16x8 o;
#pragma unroll
    for (int j = 0; j < 4; j++) { o[j] = f2bf(a[j]); o[4 + j] = f2bf(b[j]); }
    *(bf16x8*)&qdb[i * 8] = o;
    a = m4[2 * i]; b = m4[2 * i + 1];
#pragma unroll
    for (int j = 0; j < 4; j++) { o[j] = f2bf(a[j]); o[4 + j] = f2bf(b[j]); }
    *(bf16x8*)&mdb[i * 8] = o;
}

// ---------------------------------------------------------------------------
// Tiled transpose+cast of the five 512x512 weight matrices (z selects).
// out[n*512+a] = in[a*512+n] * scale  (qw gets 1/8 folded in)
// ---------------------------------------------------------------------------
__global__ __launch_bounds__(256) void transpose_cast(
    const float* __restrict__ qw, const float* __restrict__ kw,
    const float* __restrict__ vw, const float* __restrict__ gw,
    const float* __restrict__ ow,
    __bf16* __restrict__ qwt, __bf16* __restrict__ kwt,
    __bf16* __restrict__ vwt, __bf16* __restrict__ gwt,
    __bf16* __restrict__ owt)
{
    __shared__ float tile[64][65];
    const int z = blockIdx.z;
    const float* src = (z == 0) ? qw : (z == 1) ? kw : (z == 2) ? vw : (z == 3) ? gw : ow;
    __bf16* dst = (z == 0) ? qwt : (z == 1) ? kwt : (z == 2) ? vwt : (z == 3) ? gwt : owt;
    const float scale = (z == 0) ? 0.125f : 1.0f;
    const int a0 = blockIdx.x * 64, n0 = blockIdx.y * 64;
    const int t = threadIdx.x, tr = t >> 4, tc = (t & 15) * 4;
#pragma unroll
    for (int ii = 0; ii < 4; ii++) {
        f32x4 v = *(const f32x4*)&src[(a0 + tr + 16 * ii) * 512 + n0 + tc];
#pragma unroll
        for (int j = 0; j < 4; j++) tile[tr + 16 * ii][tc + j] = v[j] * scale;
    }
    __syncthreads();
#pragma unroll
    for (int ii = 0; ii < 4; ii++) {
        const int nr = tr + 16 * ii;
        bf16x4 o;
#pragma unroll
        for (int j = 0; j < 4; j++) o[j] = f2bf(tile[tc + j][nr]);
        *(bf16x4*)&dst[(n0 + nr) * 512 + a0 + tc] = o;
    }
}

// ---------------------------------------------------------------------------
// 64x64-tile bf16 GEMM core, K=512, async global_load_lds staging (m97 style).
// ---------------------------------------------------------------------------
static __device__ __forceinline__ void gemm_core64(
    const __bf16* __restrict__ A, const __bf16* __restrict__ Bt,
    __bf16* As, __bf16* Bs, int m0, int n0, int t, f32x4 acc[4])
{
    const int w = t >> 6, quad = (t >> 4) & 3, col = t & 15;
    const int sr = t >> 2, sc = (t & 3) * 8;
    for (int kk = 0; kk < 512; kk += 32) {
        __syncthreads();
        async16(&A[(m0 + sr) * 512 + kk + sc], &As[w * 512]);
        async16(&Bt[(n0 + sr) * 512 + kk + sc], &Bs[w * 512]);
        __syncthreads();
        bf16x8 af = *(const bf16x8*)&As[(w * 16 + col) * 32 + quad * 8];
#pragma unroll
        for (int ns = 0; ns < 4; ns++) {
            bf16x8 bfr = *(const bf16x8*)&Bs[(ns * 16 + col) * 32 + quad * 8];
            acc[ns] = __builtin_amdgcn_mfma_f32_16x16x32_bf16(af, bfr, acc[ns], 0, 0, 0);
        }
    }
}

// ---------------------------------------------------------------------------
// Merged projection GEMMs: z=0 q (b,h,pos,c); z=1 k (b,h,pos,c);
// z=2 v transposed (b,h,c,pos); z=3 gate sigmoid (m,512).
// ---------------------------------------------------------------------------
__global__ __launch_bounds__(256) void proj_gemm(
    const __bf16* __restrict__ qdb, const __bf16* __restrict__ mdb,
    const __bf16* __restrict__ qwt, const __bf16* __restrict__ kwt,
    const __bf16* __restrict__ vwt, const __bf16* __restrict__ gwt,
    __bf16* __restrict__ qbuf, __bf16* __restrict__ kbuf,
    __bf16* __restrict__ vt, __bf16* __restrict__ gate,
    const float* __restrict__ gb)
{
    __shared__ __attribute__((aligned(16))) __bf16 As[2048];
    __shared__ __attribute__((aligned(16))) __bf16 Bs[2048];
    const int z = blockIdx.z;
    const __bf16* A = (z == 0 || z == 3) ? qdb : mdb;
    const __bf16* Bt = (z == 0) ? qwt : (z == 1) ? kwt : (z == 2) ? vwt : gwt;
    const int m0 = blockIdx.x * 64, n0 = blockIdx.y * 64;
    f32x4 acc[4];
#pragma unroll
    for (int i = 0; i < 4; i++) acc[i] = (f32x4){0.f, 0.f, 0.f, 0.f};
    gemm_core64(A, Bt, As, Bs, m0, n0, threadIdx.x, acc);

    const int t = threadIdx.x, w = t >> 6, quad = (t >> 4) & 3, col = t & 15;
    const int mrow0 = m0 + w * 16 + quad * 4;
#pragma unroll
    for (int ns = 0; ns < 4; ns++) {
        const int ncol = n0 + ns * 16 + col;
#pragma unroll
        for (int r = 0; r < 4; r++) {
            const int m = mrow0 + r;
            const float v = acc[ns][r];
            if (z <= 1) {
                int b = m >> 10, pos = m & 1023, hh = ncol >> 6, c = ncol & 63;
                __bf16* o = z ? kbuf : qbuf;
                o[(((b * 8 + hh) * 1024 + pos) << 6) + c] = f2bf(v);
            } else if (z == 2) {
                int b = m >> 10, pos = m & 1023, hh = ncol >> 6, c = ncol & 63;
                vt[((((b * 8 + hh) << 6) + c) << 10) + pos] = f2bf(v);
            } else {
                float g = 1.0f / (1.0f + __expf(-(v + gb[ncol])));
                gate[m * 512 + ncol] = f2bf(g);
            }
        }
    }
}

// ---------------------------------------------------------------------------
// Output GEMM: out[m,n] = wavg @ ow_t + output_b  (f32 out)
// ---------------------------------------------------------------------------
__global__ __launch_bounds__(256) void out_gemm(
    const __bf16* __restrict__ A, const __bf16* __restrict__ Bt,
    float* __restrict__ outp, const float* __restrict__ bvec)
{
    __shared__ __attribute__((aligned(16))) __bf16 As[2048];
    __shared__ __attribute__((aligned(16))) __bf16 Bs[2048];
    const int m0 = blockIdx.x * 64, n0 = blockIdx.y * 64;
    f32x4 acc[4];
#pragma unroll
    for (int i = 0; i < 4; i++) acc[i] = (f32x4){0.f, 0.f, 0.f, 0.f};
    gemm_core64(A, Bt, As, Bs, m0, n0, threadIdx.x, acc);

    const int t = threadIdx.x, w = t >> 6, quad = (t >> 4) & 3, col = t & 15;
    const int mrow0 = m0 + w * 16 + quad * 4;
#pragma unroll
    for (int ns = 0; ns < 4; ns++) {
        const int ncol = n0 + ns * 16 + col;
#pragma unroll
        for (int r = 0; r < 4; r++)
            outp[(mrow0 + r) * 512 + ncol] = acc[ns][r] + bvec[ncol];
    }
}

// ---------------------------------------------------------------------------
// Attention, max-free flash: per block (b,h, 64 q-rows), 16 key-blocks of 64.
// Double-buffered async k/v staging, XOR-swizzled LDS chunks, deferred l-sum.
// Writes raw logits (nontemporal) to d_out, gated weighted avg (bf16) to wout.
// ---------------------------------------------------------------------------
__global__ __launch_bounds__(256) void attn_kernel(
    const __bf16* __restrict__ qb, const __bf16* __restrict__ kb,
    const __bf16* __restrict__ vt, const float* __restrict__ bias,
    const float* __restrict__ nb, const __bf16* __restrict__ gate,
    float* __restrict__ logits_out, __bf16* __restrict__ wout)
{
    __shared__ __attribute__((aligned(16))) __bf16 qs[4096];
    __shared__ __attribute__((aligned(16))) __bf16 ks[2][4096];
    __shared__ __attribute__((aligned(16))) __bf16 vs[2][4096];
    __shared__ __attribute__((aligned(16))) __bf16 ps[4][1152];   // 16 rows x 72 (pad)

    const int bh = blockIdx.y, b = bh >> 3, h = bh & 7;
    const int q0 = blockIdx.x * 64;
    const int t = threadIdx.x, lane = t & 63, w = t >> 6;
    const int quad = lane >> 4, col = lane & 15;

    const __bf16* qg = qb + (bh * 1024 + q0) * 64;
    const __bf16* kg = kb + bh * 65536;
    const __bf16* vg = vt + bh * 65536;
    float* lg = logits_out + (size_t)(bh * 1024 + q0) * 1024;
    const float* nbg = nb + (size_t)(h * 1024 + q0) * 1024;
    const float* biasg = bias + b * 1024;

    // staging geometry: thread t stages 16B chunk t (row r0, chunk c0), with
    // XOR swizzle: LDS chunk (r,c) holds global chunk c^(r&7) of row r.
    const int r0 = t >> 3, c0 = t & 7;
    const int sw = ((c0 ^ (r0 & 7)) << 3);

    async16(&qg[r0 * 64 + sw], &qs[w * 512]);
    async16(&qg[(r0 + 32) * 64 + sw], &qs[2048 + w * 512]);
    async16(&kg[r0 * 64 + sw], &ks[0][w * 512]);
    async16(&kg[(r0 + 32) * 64 + sw], &ks[0][2048 + w * 512]);
    async16(&vg[r0 * 1024 + sw], &vs[0][w * 512]);
    async16(&vg[(r0 + 32) * 1024 + sw], &vs[0][2048 + w * 512]);

    f32x4 o_acc[4];
#pragma unroll
    for (int i = 0; i < 4; i++) o_acc[i] = (f32x4){0.f, 0.f, 0.f, 0.f};
    float lsum[4] = {0.f, 0.f, 0.f, 0.f};

    __bf16* pw = ps[w];
    // fragment-read swizzle: logical chunk (kst*4+quad) ^ (row&7), row&7 = col&7
    const int sw0 = ((quad ^ (col & 7)) << 3);
    const int sw1 = (((quad + 4) ^ (col & 7)) << 3);
    const int arow = (w * 16 + col) * 64;

    for (int kbi = 0; kbi < 16; kbi++) {
        __syncthreads();    // drains cur-buffer async loads; protects LDS reuse
        const int cur = kbi & 1;
        if (kbi < 15) {     // prefetch next tile into other buffer (in flight during compute)
            const int nx = cur ^ 1;
            const __bf16* kgn = kg + (kbi + 1) * 4096;
            const __bf16* vgn = vg + (kbi + 1) * 64;
            async16(&kgn[r0 * 64 + sw], &ks[nx][w * 512]);
            async16(&kgn[(r0 + 32) * 64 + sw], &ks[nx][2048 + w * 512]);
            async16(&vgn[r0 * 1024 + sw], &vs[nx][w * 512]);
            async16(&vgn[(r0 + 32) * 1024 + sw], &vs[nx][2048 + w * 512]);
        }
        const __bf16* kc = ks[cur];
        const __bf16* vc = vs[cur];

        // S = q @ k^T
        f32x4 s[4];
#pragma unroll
        for (int i = 0; i < 4; i++) s[i] = (f32x4){0.f, 0.f, 0.f, 0.f};
        bf16x8 af0 = *(const bf16x8*)&qs[arow + sw0];
        bf16x8 af1 = *(const bf16x8*)&qs[arow + sw1];
#pragma unroll
        for (int ns = 0; ns < 4; ns++) {
            bf16x8 b0 = *(const bf16x8*)&kc[(ns * 16 + col) * 64 + sw0];
            s[ns] = __builtin_amdgcn_mfma_f32_16x16x32_bf16(af0, b0, s[ns], 0, 0, 0);
            bf16x8 b1 = *(const bf16x8*)&kc[(ns * 16 + col) * 64 + sw1];
            s[ns] = __builtin_amdgcn_mfma_f32_16x16x32_bf16(af1, b1, s[ns], 0, 0, 0);
        }

        // max-free softmax: store raw logits, p = exp(raw + bias + nb)
        float* lrow = lg + (w * 16 + quad * 4) * 1024 + kbi * 64 + col;
        const float* nrow = nbg + (w * 16 + quad * 4) * 1024 + kbi * 64 + col;
#pragma unroll
        for (int ns = 0; ns < 4; ns++) {
            const float bval = biasg[kbi * 64 + ns * 16 + col];
#pragma unroll
            for (int r = 0; r < 4; r++) {
                float raw = s[ns][r];
                __builtin_nontemporal_store(raw, &lrow[r * 1024 + ns * 16]);
                float p = __expf(raw + bval + nrow[r * 1024 + ns * 16]);
                lsum[r] += p;
                pw[(quad * 4 + r) * 72 + ns * 16 + col] = (__bf16)p;
            }
        }

        // O += P @ V
        bf16x8 pf0 = *(const bf16x8*)&pw[col * 72 + quad * 8];
        bf16x8 pf1 = *(const bf16x8*)&pw[col * 72 + 32 + quad * 8];
#pragma unroll
        for (int ns = 0; ns < 4; ns++) {
            bf16x8 v0 = *(const bf16x8*)&vc[(ns * 16 + col) * 64 + sw0];
            o_acc[ns] = __builtin_amdgcn_mfma_f32_16x16x32_bf16(pf0, v0, o_acc[ns], 0, 0, 0);
            bf16x8 v1 = *(const bf16x8*)&vc[(ns * 16 + col) * 64 + sw1];
            o_acc[ns] = __builtin_amdgcn_mfma_f32_16x16x32_bf16(pf1, v1, o_acc[ns], 0, 0, 0);
        }
    }

    // one deferred l-sum reduction across the 16 cols
#pragma unroll
    for (int mask = 1; mask < 16; mask <<= 1) {
#pragma unroll
        for (int r = 0; r < 4; r++) lsum[r] += __shfl_xor(lsum[r], mask);
    }
    float inv[4];
#pragma unroll
    for (int r = 0; r < 4; r++) inv[r] = 1.0f / lsum[r];

#pragma unroll
    for (int ns = 0; ns < 4; ns++) {
        const int c = ns * 16 + col;
#pragma unroll
        for (int r = 0; r < 4; r++) {
            const int pos = q0 + w * 16 + quad * 4 + r;
            float ov = o_acc[ns][r] * inv[r];
            float gv = (float)gate[(b * 1024 + pos) * 512 + h * 64 + c];
            wout[(b * 1024 + pos) * 512 + h * 64 + c] = f2bf(ov * gv);
        }
    }
}

// ---------------------------------------------------------------------------
extern "C" void kernel_launch(void* const* d_in, const int* in_sizes, int n_in,
                              void* d_out, int out_size, void* d_ws, size_t ws_size,
                              hipStream_t stream) {
    (void)in_sizes; (void)n_in; (void)out_size; (void)ws_size;
    const float* q_data   = (const float*)d_in[0];
    const float* m_data   = (const float*)d_in[1];
    const float* bias     = (const float*)d_in[2];
    const float* nbb      = (const float*)d_in[3];
    const float* query_w  = (const float*)d_in[4];
    const float* key_w    = (const float*)d_in[5];
    const float* value_w  = (const float*)d_in[6];
    const float* gating_w = (const float*)d_in[7];
    const float* gating_b = (const float*)d_in[8];
    const float* output_w = (const float*)d_in[9];
    const float* output_b = (const float*)d_in[10];

    char* ws = (char*)d_ws;
    __bf16* qd_b  = (__bf16*)(ws + 0);         // 4 MiB (reused as wavg later)
    __bf16* md_b  = (__bf16*)(ws + 4194304);   // 4 MiB
    __bf16* qw_t  = (__bf16*)(ws + 8388608);   // 512 KiB each
    __bf16* kw_t  = (__bf16*)(ws + 8912896);
    __bf16* vw_t  = (__bf16*)(ws + 9437184);
    __bf16* gw_t  = (__bf16*)(ws + 9961472);
    __bf16* ow_t  = (__bf16*)(ws + 10485760);
    __bf16* q_buf = (__bf16*)(ws + 11010048);  // 4 MiB (b,h,pos,c)
    __bf16* k_buf = (__bf16*)(ws + 15204352);  // 4 MiB (b,h,pos,c)
    __bf16* v_t   = (__bf16*)(ws + 19398656);  // 4 MiB (b,h,c,pos)
    __bf16* gate  = (__bf16*)(ws + 23592960);  // 4 MiB (m,512)
    __bf16* wavg  = (__bf16*)(ws + 0);         // overlays qd_b (dead by then)

    float* outp = (float*)d_out;
    float* logits = outp + (4 * 1024 * 512);

    cast_data<<<dim3(1024), dim3(256), 0, stream>>>(q_data, m_data, qd_b, md_b);
    transpose_cast<<<dim3(8, 8, 5), dim3(256), 0, stream>>>(
        query_w, key_w, value_w, gating_w, output_w, qw_t, kw_t, vw_t, gw_t, ow_t);
    proj_gemm<<<dim3(64, 8, 4), dim3(256), 0, stream>>>(
        qd_b, md_b, qw_t, kw_t, vw_t, gw_t, q_buf, k_buf, v_t, gate, gating_b);
    attn_kernel<<<dim3(16, 32), dim3(256), 0, stream>>>(
        q_buf, k_buf, v_t, bias, nbb, gate, logits, wavg);
    out_gemm<<<dim3(64, 8), dim3(256), 0, stream>>>(wavg, ow_t, outp, output_b);
}